// Round 1
// baseline (376.611 us; speedup 1.0000x reference)
//
#include <hip/hip_runtime.h>

#define BLANKC 59
#define NEGF (-1e30f)

__device__ __forceinline__ float lae3(float a, float b, float c) {
    float m = fmaxf(a, fmaxf(b, c));
    return m + __logf(__expf(a - m) + __expf(b - m) + __expf(c - m));
}

// One wave (64 threads) per batch element. Lane owns extended positions
// s0 = lane and s1 = lane + 64 (S = 91, so lanes 0..26 have a valid s1).
__global__ __launch_bounds__(64)
void ctc_fwd(const int* __restrict__ labels, const float* __restrict__ logits,
             float* __restrict__ out, int T, int V, int L, float inv_b) {
    const int b    = blockIdx.x;
    const int lane = threadIdx.x;
    const int S    = 2 * L + 1;   // 91

    __shared__ float row[64];        // current log-softmax numerators (raw logits)
    __shared__ float alpha_sh[128];  // final alpha gather

    const int*   lab = labels + (long)b * L;
    const float* lg  = logits + (long)b * T * V;

    // --- per-lane extended-label values and skip-transition flags ---
    const int s1 = lane + 64;
    int e0 = (lane & 1) ? lab[(lane - 1) >> 1] : BLANKC;
    int e1 = BLANKC;
    if (s1 < S && (s1 & 1)) e1 = lab[(s1 - 1) >> 1];
    bool skip0 = false, skip1 = false;
    if ((lane & 1) && lane >= 3)
        skip0 = (e0 != BLANKC) && (e0 != lab[(lane - 3) >> 1]);
    if (s1 < S && (s1 & 1))
        skip1 = (e1 != BLANKC) && (e1 != lab[(s1 - 3) >> 1]);

    // label length (number of non-pad tokens)
    unsigned long long mk = __ballot((lane < L) && (lab[lane] != BLANKC));
    const int len = __popcll(mk);

    auto ldrow = [&](int t) -> float {
        return (lane < V) ? lg[(long)t * V + lane] : NEGF;
    };

    // depth-3 register prefetch pipeline for logits rows
    float xa = ldrow(0);
    float xb = (T > 1) ? ldrow(1) : NEGF;
    float xc = (T > 2) ? ldrow(2) : NEGF;

    float a0 = NEGF, a1 = NEGF;

    for (int t = 0; t < T; ++t) {
        float x = xa; xa = xb; xb = xc;
        xc = (t + 3 < T) ? ldrow(t + 3) : NEGF;

        // wave-wide log-sum-exp over V=60 (lanes >= V carry -1e30 -> exp 0)
        float m = x;
        #pragma unroll
        for (int off = 32; off > 0; off >>= 1) m = fmaxf(m, __shfl_xor(m, off, 64));
        float e = __expf(x - m);
        #pragma unroll
        for (int off = 32; off > 0; off >>= 1) e += __shfl_xor(e, off, 64);
        const float lse = m + __logf(e);

        // stage row in LDS for the ext-index gather (single wave: barriers cheap)
        __syncthreads();
        row[lane] = x;
        __syncthreads();
        const float em0 = row[e0] - lse;
        const float em1 = row[e1] - lse;   // e1 clamped to BLANK for invalid s1

        if (t == 0) {
            // alpha0: only s=0 (blank) and s=1 (first label) reachable
            a0 = (lane <= 1) ? em0 : NEGF;
            // a1 stays NEGF
        } else {
            float u01 = __shfl_up(a0, 1, 64);   // alpha[s0-1]
            float u02 = __shfl_up(a0, 2, 64);   // alpha[s0-2]
            float u11 = __shfl_up(a1, 1, 64);   // alpha[s1-1]
            float u12 = __shfl_up(a1, 2, 64);   // alpha[s1-2]
            const float a63 = __shfl(a0, 63, 64);
            const float a62 = __shfl(a0, 62, 64);
            if (lane == 0)      { u01 = NEGF; u02 = NEGF; u11 = a63; u12 = a62; }
            else if (lane == 1) { u02 = NEGF; u12 = a63; }
            a0 = lae3(a0, u01, skip0 ? u02 : NEGF) + em0;
            a1 = lae3(a1, u11, skip1 ? u12 : NEGF) + em1;
        }
    }

    // gather final alpha and reduce to nll
    __syncthreads();
    alpha_sh[lane]      = a0;
    alpha_sh[lane + 64] = a1;
    __syncthreads();
    if (lane == 0) {
        const int end = 2 * len;                 // index of final blank
        const float ab2 = alpha_sh[end];
        const float al2 = (end > 0) ? alpha_sh[end - 1] : NEGF;
        const float mm  = fmaxf(ab2, al2);
        const float nll = -(mm + __logf(__expf(ab2 - mm) + __expf(al2 - mm)));
        atomicAdd(out, nll * inv_b);
    }
}

extern "C" void kernel_launch(void* const* d_in, const int* in_sizes, int n_in,
                              void* d_out, int out_size, void* d_ws, size_t ws_size,
                              hipStream_t stream) {
    const int* labels   = (const int*)d_in[0];
    const float* logits = (const float*)d_in[1];
    float* out          = (float*)d_out;

    const int L = 45, V = 60;
    const int B = in_sizes[0] / L;
    const int T = in_sizes[1] / (B * V);

    hipMemsetAsync(out, 0, (size_t)out_size * sizeof(float), stream);
    ctc_fwd<<<B, 64, 0, stream>>>(labels, logits, out, T, V, L, 1.0f / (float)B);
}